// Round 3
// baseline (269.706 us; speedup 1.0000x reference)
//
#include <hip/hip_runtime.h>

#define B   2
#define N   32768
#define NC  1024
#define S   32
#define NSP (NC * S)   // 32768

#define CHUNK 1024              // xyz rows per LDS buffer
#define NCH   (N / CHUNK)       // 32
#define BLKT  256               // threads (4 waves)
#define COLS_BLK 256            // 4 waves * 2 frags * 32 cols
#define GRIDX (NSP / COLS_BLK)  // 128

typedef __attribute__((ext_vector_type(8)))  short short8v;
typedef __attribute__((ext_vector_type(16))) float f32x16;
typedef const __attribute__((address_space(1))) void gvoid_t;
typedef __attribute__((address_space(3))) void svoid_t;

static __device__ __forceinline__ unsigned short f2b(float x) {
    unsigned u = __float_as_uint(x);
    return (unsigned short)((u + 0x7FFFu + ((u >> 16) & 1u)) >> 16);   // RNE
}
static __device__ __forceinline__ float b2f(unsigned short u) {
    return __uint_as_float(((unsigned)u) << 16);
}
static __device__ __forceinline__ float min3f(float a, float b, float c) {
    return fminf(fminf(a, b), c);   // fuses to v_min3_f32
}

// ws layout: Afrag (2 MB) | best u64 (512 KB) | acc[4] + counter (32 B)

// ---- kernel 1: build A-fragments + init best/acc -------------------------
__global__ __launch_bounds__(256) void k_prep(const float* __restrict__ xyz,
                                              unsigned short* __restrict__ Afrag,
                                              unsigned long long* __restrict__ best,
                                              unsigned* __restrict__ accw) {
    int i = blockIdx.x * 256 + threadIdx.x;   // [0, B*N)
    if (i < 8) accw[i] = 0u;                  // acc[4] floats + counter + pad
    best[i] = ~0ull;

    const float* q = xyz + (size_t)i * 3;
    float qx = q[0], qy = q[1], qz = q[2];
    float h = 0.5f * (qx * qx + qy * qy + qz * qz);
    unsigned short xh = f2b(-qx), yh = f2b(-qy), zh = f2b(-qz);
    unsigned short xl = f2b(-qx - b2f(xh));
    unsigned short yl = f2b(-qy - b2f(yh));
    unsigned short zl = f2b(-qz - b2f(zh));
    unsigned short hh = f2b(h), hl = f2b(h - b2f(hh));

    int b = i >> 15, j = i & (N - 1);
    int tile = j >> 5, r = j & 31;
    unsigned short* base = Afrag + ((size_t)b * N + (size_t)tile * 32) * 16;
    uint4 s0, s1;
    s0.x = (unsigned)xh | ((unsigned)yh << 16);
    s0.y = (unsigned)zh | ((unsigned)xl << 16);
    s0.z = (unsigned)yl | ((unsigned)zl << 16);
    s0.w = (unsigned)xh | ((unsigned)yh << 16);
    s1.x = (unsigned)zh | ((unsigned)hh << 16);
    s1.y = (unsigned)hl;
    s1.z = 0u; s1.w = 0u;
    *(uint4*)(base + (size_t)r * 8)        = s0;   // k=0..7   lane r
    *(uint4*)(base + (size_t)(r + 32) * 8) = s1;   // k=8..15  lane r+32
}

// ---- kernel 2: per point, argmin over a 256-center slice -> u64 atomicMin -
__global__ __launch_bounds__(256) void k_p2c(const float* __restrict__ centers,
                                             const float* __restrict__ xyz,
                                             unsigned long long* __restrict__ best) {
    __shared__ float4 c4[256];
    const int b = blockIdx.z, qb = blockIdx.y, tid = threadIdx.x;

    const float* cb = centers + ((size_t)b * NC + qb * 256) * 3;
    for (int g = tid; g < 64; g += 256) {
        float4 f0 = ((const float4*)cb)[g * 3 + 0];
        float4 f1 = ((const float4*)cb)[g * 3 + 1];
        float4 f2 = ((const float4*)cb)[g * 3 + 2];
        float x0 = f0.x, y0 = f0.y, z0 = f0.z;
        float x1 = f0.w, y1 = f1.x, z1 = f1.y;
        float x2 = f1.z, y2 = f1.w, z2 = f2.x;
        float x3 = f2.y, y3 = f2.z, z3 = f2.w;
        c4[g * 4 + 0] = make_float4(x0, y0, z0, 0.5f * (x0 * x0 + y0 * y0 + z0 * z0));
        c4[g * 4 + 1] = make_float4(x1, y1, z1, 0.5f * (x1 * x1 + y1 * y1 + z1 * z1));
        c4[g * 4 + 2] = make_float4(x2, y2, z2, 0.5f * (x2 * x2 + y2 * y2 + z2 * z2));
        c4[g * 4 + 3] = make_float4(x3, y3, z3, 0.5f * (x3 * x3 + y3 * y3 + z3 * z3));
    }
    __syncthreads();

    const int pi = blockIdx.x * 256 + tid;
    const float* p = xyz + ((size_t)b * N + pi) * 3;
    const float px = p[0], py = p[1], pz = p[2];

    float tmin = 1e30f;
    int   imin = 0;
    #pragma unroll 4
    for (int c = 0; c < 256; ++c) {
        float4 q = c4[c];
        float  t = q.w - px * q.x - py * q.y - pz * q.z;
        if (t < tmin) { tmin = t; imin = c; }
    }
    unsigned bits = __float_as_uint(tmin);
    unsigned ord  = (bits & 0x80000000u) ? ~bits : (bits | 0x80000000u);
    unsigned long long key =
        ((unsigned long long)ord << 32) | (unsigned)(qb * 256 + imin);
    atomicMin(best + (size_t)b * N + pi, key);
}

// ---- kernel 3: MFMA sphere->points min + in-wave group max ---------------
__global__ __launch_bounds__(BLKT) void k_sp2p(const float* __restrict__ sp,
                                               const unsigned short* __restrict__ Afrag,
                                               float* __restrict__ acc_c) {
    __shared__ unsigned short lds[2][CHUNK * 16];   // 2 x 32 KB
    const int b = blockIdx.y;
    const int tid = threadIdx.x, wid = tid >> 6, lane = tid & 63;
    const char* src = (const char*)(Afrag + (size_t)b * N * 16);

#define STAGE(BUF, CH) do {                                                   \
        const char* s_ = src + (size_t)(CH) * (CHUNK * 32);                   \
        char* l_ = (char*)lds[BUF];                                           \
        _Pragma("unroll")                                                     \
        for (int it_ = 0; it_ < 8; ++it_) {                                   \
            int off_ = it_ * 4096 + wid * 1024;                               \
            __builtin_amdgcn_global_load_lds((gvoid_t*)(s_ + off_ + lane*16), \
                                             (svoid_t*)(l_ + off_), 16, 0, 0);\
        }                                                                     \
    } while (0)

    STAGE(0, 0);

    // two B-fragments per wave: cols [base, base+32)
    const int colbase = blockIdx.x * COLS_BLK + wid * 64 + (lane & 31);
    float pp[2]; short8v bf[2];
    #pragma unroll
    for (int f = 0; f < 2; ++f) {
        const float* p = sp + ((size_t)b * NSP + colbase + f * 32) * 3;
        float px = p[0], py = p[1], pz = p[2];
        pp[f] = px * px + py * py + pz * pz;
        unsigned short xh = f2b(px), yh = f2b(py), zh = f2b(pz);
        unsigned short xl = f2b(px - b2f(xh));
        unsigned short yl = f2b(py - b2f(yh));
        unsigned short zl = f2b(pz - b2f(zh));
        short8v v;
        if (lane < 32) {
            v[0] = (short)xh; v[1] = (short)yh; v[2] = (short)zh;
            v[3] = (short)xh; v[4] = (short)yh; v[5] = (short)zh;
            v[6] = (short)xl; v[7] = (short)yl;
        } else {
            v[0] = (short)zl; v[1] = (short)0x3F80; v[2] = (short)0x3F80;
            v[3] = 0; v[4] = 0; v[5] = 0; v[6] = 0; v[7] = 0;
        }
        bf[f] = v;
    }
    f32x16 zero;
    #pragma unroll
    for (int i = 0; i < 16; ++i) zero[i] = 0.0f;

    float run0 = 1e30f, run1 = 1e30f;
    int buf = 0;
    __syncthreads();   // drains vmcnt of STAGE(0,0)

    for (int ch = 0; ch < NCH; ++ch) {
        if (ch + 1 < NCH) STAGE(buf ^ 1, ch + 1);
        const unsigned short* ap = lds[buf] + lane * 8;
        #pragma unroll 4
        for (int t = 0; t < CHUNK / 32; ++t) {
            short8v a = *(const short8v*)(ap + (size_t)t * 512);
            f32x16 a0 = __builtin_amdgcn_mfma_f32_32x32x16_bf16(a, bf[0], zero, 0, 0, 0);
            f32x16 a1 = __builtin_amdgcn_mfma_f32_32x32x16_bf16(a, bf[1], zero, 0, 0, 0);
            {
                float m0 = min3f(a0[0], a0[1], a0[2]);
                float m1 = min3f(a0[3], a0[4], a0[5]);
                float m2 = min3f(a0[6], a0[7], a0[8]);
                float m3 = min3f(a0[9], a0[10], a0[11]);
                float m4 = min3f(a0[12], a0[13], a0[14]);
                float n0 = min3f(m0, m1, a0[15]);
                float n1 = min3f(m2, m3, m4);
                run0 = min3f(run0, n0, n1);
            }
            {
                float m0 = min3f(a1[0], a1[1], a1[2]);
                float m1 = min3f(a1[3], a1[4], a1[5]);
                float m2 = min3f(a1[6], a1[7], a1[8]);
                float m3 = min3f(a1[9], a1[10], a1[11]);
                float m4 = min3f(a1[12], a1[13], a1[14]);
                float n0 = min3f(m0, m1, a1[15]);
                float n1 = min3f(m2, m3, m4);
                run1 = min3f(run1, n0, n1);
            }
        }
        __syncthreads();   // drains stage vmcnt + all ds_reads of buf
        buf ^= 1;
    }

    // cross-half min (lanes l and l^32 hold same col), then 32-col group max
    run0 = fminf(run0, __shfl_xor(run0, 32, 64));
    run1 = fminf(run1, __shfl_xor(run1, 32, 64));
    float sq0 = fmaxf(2.0f * run0 + pp[0], 0.0f);
    float sq1 = fmaxf(2.0f * run1 + pp[1], 0.0f);
    #pragma unroll
    for (int o = 16; o > 0; o >>= 1) {
        sq0 = fmaxf(sq0, __shfl_xor(sq0, o, 64));
        sq1 = fmaxf(sq1, __shfl_xor(sq1, o, 64));
    }
    if (lane == 0) {
        float cd = sqrtf(fmaxf(sq0, 1e-12f)) + sqrtf(fmaxf(sq1, 1e-12f));
        atomicAdd(&acc_c[b], cd);
    }
#undef STAGE
}

// ---- kernel 4: finalize p2c term + ticketed final scalar -----------------
__global__ __launch_bounds__(256) void k_pfin(const unsigned long long* __restrict__ best,
                                              const float* __restrict__ xyz,
                                              const float* __restrict__ radius,
                                              float* __restrict__ acc,
                                              unsigned* __restrict__ counter,
                                              float* __restrict__ out) {
    const int tid = threadIdx.x;
    const int i = blockIdx.x * 256 + tid;   // [0, B*N)
    const int b = i >> 15;
    unsigned long long k = best[i];
    int idx = (int)(k & 0xFFFFFFFFu);
    unsigned ord  = (unsigned)(k >> 32);
    unsigned bits = (ord & 0x80000000u) ? (ord ^ 0x80000000u) : ~ord;
    float tmin = __uint_as_float(bits);

    const float* p = xyz + (size_t)i * 3;
    float pp = p[0] * p[0] + p[1] * p[1] + p[2] * p[2];
    float sq = 2.0f * tmin + pp;
    float cd = sqrtf(fmaxf(sq, 1e-12f));
    float val = fmaxf(cd - radius[(size_t)b * NC + idx], 0.0f);

    #pragma unroll
    for (int o = 32; o > 0; o >>= 1) val += __shfl_down(val, o);
    __shared__ float wsum[4];
    if ((tid & 63) == 0) wsum[tid >> 6] = val;
    __syncthreads();
    if (tid == 0) atomicAdd(&acc[b], wsum[0] + wsum[1] + wsum[2] + wsum[3]);

    __shared__ int lastf;
    if (tid == 0) {
        __threadfence();
        unsigned old = atomicAdd(counter, 1u);
        lastf = (old == (unsigned)(gridDim.x - 1));
    }
    __syncthreads();
    if (lastf && tid == 0) {
        float p0 = atomicAdd(&acc[0], 0.0f), p1 = atomicAdd(&acc[1], 0.0f);
        float c0 = atomicAdd(&acc[2], 0.0f), c1 = atomicAdd(&acc[3], 0.0f);
        out[0] = ((c0 + c1) / (float)NC + (p0 + p1) / (float)N) * 0.5f;
    }
}

extern "C" void kernel_launch(void* const* d_in, const int* in_sizes, int n_in,
                              void* d_out, int out_size, void* d_ws, size_t ws_size,
                              hipStream_t stream) {
    const float* centers = (const float*)d_in[0];
    const float* radius  = (const float*)d_in[1];
    const float* xyz     = (const float*)d_in[2];
    const float* sp      = (const float*)d_in[3];
    float* out = (float*)d_out;

    unsigned short*     Afrag = (unsigned short*)d_ws;                       // 2 MB
    unsigned long long* best  = (unsigned long long*)((char*)d_ws + (size_t)B * N * 32);
    float*    acc     = (float*)((char*)best + (size_t)B * N * 8);           // 4 floats
    unsigned* counter = (unsigned*)(acc + 4);

    hipLaunchKernelGGL(k_prep, dim3(B * N / 256), dim3(256), 0, stream,
                       xyz, Afrag, best, (unsigned*)acc);
    hipLaunchKernelGGL(k_p2c, dim3(N / 256, NC / 256, B), dim3(256), 0, stream,
                       centers, xyz, best);
    hipLaunchKernelGGL(k_sp2p, dim3(GRIDX, B), dim3(BLKT), 0, stream,
                       sp, Afrag, acc + 2);
    hipLaunchKernelGGL(k_pfin, dim3(B * N / 256), dim3(256), 0, stream,
                       best, xyz, radius, acc, counter, out);
}

// Round 4
// 145.221 us; speedup vs baseline: 1.8572x; 1.8572x over previous
//
#include <hip/hip_runtime.h>

#define B   2
#define N   32768
#define NC  1024
#define S   32
#define NSP (NC * S)   // 32768

#define CHUNK 2048              // xyz rows staged per block (64 KB)
#define NCH   (N / CHUNK)       // 16
#define BLKT  512               // 8 waves
#define COLS_BLK 512            // 8 waves * 2 frags * 32 cols
#define GRIDX (NSP / COLS_BLK)  // 64

typedef __attribute__((ext_vector_type(8)))  short short8v;
typedef __attribute__((ext_vector_type(16))) float f32x16;
typedef const __attribute__((address_space(1))) void gvoid_t;
typedef __attribute__((address_space(3))) void svoid_t;

static __device__ __forceinline__ unsigned short f2b(float x) {
    unsigned u = __float_as_uint(x);
    return (unsigned short)((u + 0x7FFFu + ((u >> 16) & 1u)) >> 16);   // RNE
}
static __device__ __forceinline__ float b2f(unsigned short u) {
    return __uint_as_float(((unsigned)u) << 16);
}
static __device__ __forceinline__ float min3f(float a, float b, float c) {
    return fminf(fminf(a, b), c);   // fuses to v_min3_f32
}

// ws layout: Afrag 2MB | best u64 512KB | minsq u32 256KB | acc+counter 32B

// ---- kernel 1: build A-fragments + init best/minsq/acc -------------------
__global__ __launch_bounds__(256) void k_prep(const float* __restrict__ xyz,
                                              unsigned short* __restrict__ Afrag,
                                              unsigned long long* __restrict__ best,
                                              unsigned* __restrict__ minsq,
                                              unsigned* __restrict__ accw) {
    int i = blockIdx.x * 256 + threadIdx.x;   // [0, B*N) == [0, B*NSP)
    if (i < 2) accw[i] = 0u;                  // acc float + counter
    best[i]  = ~0ull;
    minsq[i] = 0x7F800000u;                   // +inf bits

    const float* q = xyz + (size_t)i * 3;
    float qx = q[0], qy = q[1], qz = q[2];
    float h = 0.5f * (qx * qx + qy * qy + qz * qz);
    unsigned short xh = f2b(-qx), yh = f2b(-qy), zh = f2b(-qz);
    unsigned short xl = f2b(-qx - b2f(xh));
    unsigned short yl = f2b(-qy - b2f(yh));
    unsigned short zl = f2b(-qz - b2f(zh));
    unsigned short hh = f2b(h), hl = f2b(h - b2f(hh));

    int b = i >> 15, j = i & (N - 1);
    int tile = j >> 5, r = j & 31;
    unsigned short* base = Afrag + ((size_t)b * N + (size_t)tile * 32) * 16;
    uint4 s0, s1;
    s0.x = (unsigned)xh | ((unsigned)yh << 16);
    s0.y = (unsigned)zh | ((unsigned)xl << 16);
    s0.z = (unsigned)yl | ((unsigned)zl << 16);
    s0.w = (unsigned)xh | ((unsigned)yh << 16);
    s1.x = (unsigned)zh | ((unsigned)hh << 16);
    s1.y = (unsigned)hl;
    s1.z = 0u; s1.w = 0u;
    *(uint4*)(base + (size_t)r * 8)        = s0;   // k=0..7   lane r
    *(uint4*)(base + (size_t)(r + 32) * 8) = s1;   // k=8..15  lane r+32
}

// ---- kernel 2: per point, argmin over a 256-center slice -> u64 atomicMin -
__global__ __launch_bounds__(256) void k_p2c(const float* __restrict__ centers,
                                             const float* __restrict__ xyz,
                                             unsigned long long* __restrict__ best) {
    __shared__ float4 c4[256];
    const int b = blockIdx.z, qb = blockIdx.y, tid = threadIdx.x;

    const float* cb = centers + ((size_t)b * NC + qb * 256) * 3;
    for (int g = tid; g < 64; g += 256) {
        float4 f0 = ((const float4*)cb)[g * 3 + 0];
        float4 f1 = ((const float4*)cb)[g * 3 + 1];
        float4 f2 = ((const float4*)cb)[g * 3 + 2];
        float x0 = f0.x, y0 = f0.y, z0 = f0.z;
        float x1 = f0.w, y1 = f1.x, z1 = f1.y;
        float x2 = f1.z, y2 = f1.w, z2 = f2.x;
        float x3 = f2.y, y3 = f2.z, z3 = f2.w;
        c4[g * 4 + 0] = make_float4(x0, y0, z0, 0.5f * (x0 * x0 + y0 * y0 + z0 * z0));
        c4[g * 4 + 1] = make_float4(x1, y1, z1, 0.5f * (x1 * x1 + y1 * y1 + z1 * z1));
        c4[g * 4 + 2] = make_float4(x2, y2, z2, 0.5f * (x2 * x2 + y2 * y2 + z2 * z2));
        c4[g * 4 + 3] = make_float4(x3, y3, z3, 0.5f * (x3 * x3 + y3 * y3 + z3 * z3));
    }
    __syncthreads();

    const int pi = blockIdx.x * 256 + tid;
    const float* p = xyz + ((size_t)b * N + pi) * 3;
    const float px = p[0], py = p[1], pz = p[2];

    float tmin = 1e30f;
    int   imin = 0;
    #pragma unroll 4
    for (int c = 0; c < 256; ++c) {
        float4 q = c4[c];
        float  t = q.w - px * q.x - py * q.y - pz * q.z;
        if (t < tmin) { tmin = t; imin = c; }
    }
    unsigned bits = __float_as_uint(tmin);
    unsigned ord  = (bits & 0x80000000u) ? ~bits : (bits | 0x80000000u);
    unsigned long long key =
        ((unsigned long long)ord << 32) | (unsigned)(qb * 256 + imin);
    atomicMin(best + (size_t)b * N + pi, key);
}

// ---- kernel 3: MFMA (row-chunk x col-tile grid) -> u32 atomicMin ---------
__global__ __launch_bounds__(BLKT) void k_sp2p(const float* __restrict__ sp,
                                               const unsigned short* __restrict__ Afrag,
                                               unsigned* __restrict__ minsq) {
    __shared__ unsigned short lds[CHUNK * 16];   // 64 KB
    const int b = blockIdx.z, chunk = blockIdx.y;
    const int tid = threadIdx.x, wid = tid >> 6, lane = tid & 63;

    // stage 64 KB: 8 iters x (512 lanes x 16 B)
    const char* src = (const char*)(Afrag +
                        ((size_t)b * N + (size_t)chunk * CHUNK) * 16);
    #pragma unroll
    for (int it = 0; it < 8; ++it) {
        int off = it * 8192 + wid * 1024;
        __builtin_amdgcn_global_load_lds((gvoid_t*)(src + off + lane * 16),
                                         (svoid_t*)((char*)lds + off), 16, 0, 0);
    }

    // two B-fragments per wave: cols base, base+32 (overlaps staging)
    const int colbase = blockIdx.x * COLS_BLK + wid * 64 + (lane & 31);
    float pp[2]; short8v bf[2];
    #pragma unroll
    for (int f = 0; f < 2; ++f) {
        const float* p = sp + ((size_t)b * NSP + colbase + f * 32) * 3;
        float px = p[0], py = p[1], pz = p[2];
        pp[f] = px * px + py * py + pz * pz;
        unsigned short xh = f2b(px), yh = f2b(py), zh = f2b(pz);
        unsigned short xl = f2b(px - b2f(xh));
        unsigned short yl = f2b(py - b2f(yh));
        unsigned short zl = f2b(pz - b2f(zh));
        short8v v;
        if (lane < 32) {
            v[0] = (short)xh; v[1] = (short)yh; v[2] = (short)zh;
            v[3] = (short)xh; v[4] = (short)yh; v[5] = (short)zh;
            v[6] = (short)xl; v[7] = (short)yl;
        } else {
            v[0] = (short)zl; v[1] = (short)0x3F80; v[2] = (short)0x3F80;
            v[3] = 0; v[4] = 0; v[5] = 0; v[6] = 0; v[7] = 0;
        }
        bf[f] = v;
    }
    f32x16 zero;
    #pragma unroll
    for (int i = 0; i < 16; ++i) zero[i] = 0.0f;

    __syncthreads();   // staging complete

    float run0 = 1e30f, run1 = 1e30f;
    const unsigned short* ap = lds + lane * 8;
    #pragma unroll 4
    for (int t = 0; t < CHUNK / 32; ++t) {
        short8v a = *(const short8v*)(ap + (size_t)t * 512);
        f32x16 a0 = __builtin_amdgcn_mfma_f32_32x32x16_bf16(a, bf[0], zero, 0, 0, 0);
        f32x16 a1 = __builtin_amdgcn_mfma_f32_32x32x16_bf16(a, bf[1], zero, 0, 0, 0);
        {
            float m0 = min3f(a0[0], a0[1], a0[2]);
            float m1 = min3f(a0[3], a0[4], a0[5]);
            float m2 = min3f(a0[6], a0[7], a0[8]);
            float m3 = min3f(a0[9], a0[10], a0[11]);
            float m4 = min3f(a0[12], a0[13], a0[14]);
            float n0 = min3f(m0, m1, a0[15]);
            float n1 = min3f(m2, m3, m4);
            run0 = min3f(run0, n0, n1);
        }
        {
            float m0 = min3f(a1[0], a1[1], a1[2]);
            float m1 = min3f(a1[3], a1[4], a1[5]);
            float m2 = min3f(a1[6], a1[7], a1[8]);
            float m3 = min3f(a1[9], a1[10], a1[11]);
            float m4 = min3f(a1[12], a1[13], a1[14]);
            float n0 = min3f(m0, m1, a1[15]);
            float n1 = min3f(m2, m3, m4);
            run1 = min3f(run1, n0, n1);
        }
    }

    // lanes l, l^32 hold the same col: combine, then one atomic per col
    run0 = fminf(run0, __shfl_xor(run0, 32, 64));
    run1 = fminf(run1, __shfl_xor(run1, 32, 64));
    if (lane < 32) {
        float sq0 = fmaxf(2.0f * run0 + pp[0], 0.0f);
        float sq1 = fmaxf(2.0f * run1 + pp[1], 0.0f);
        unsigned* mb = minsq + (size_t)b * NSP + colbase;
        atomicMin(mb,      __float_as_uint(sq0));
        atomicMin(mb + 32, __float_as_uint(sq1));
    }
}

// ---- kernel 4: p2c finalize + group-max + ticketed final scalar ----------
__global__ __launch_bounds__(256) void k_fin(const unsigned long long* __restrict__ best,
                                             const unsigned* __restrict__ minsq,
                                             const float* __restrict__ xyz,
                                             const float* __restrict__ radius,
                                             float* __restrict__ acc,
                                             unsigned* __restrict__ counter,
                                             float* __restrict__ out) {
    const int tid = threadIdx.x;
    const int i = blockIdx.x * 256 + tid;   // [0, B*N) == [0, B*NSP)
    const int b = i >> 15;

    // p2c term
    unsigned long long k = best[i];
    int idx = (int)(k & 0xFFFFFFFFu);
    unsigned ord  = (unsigned)(k >> 32);
    unsigned bits = (ord & 0x80000000u) ? (ord ^ 0x80000000u) : ~ord;
    float tmin = __uint_as_float(bits);
    const float* p = xyz + (size_t)i * 3;
    float pp = p[0] * p[0] + p[1] * p[1] + p[2] * p[2];
    float cdp = sqrtf(fmaxf(2.0f * tmin + pp, 1e-12f));
    float val = fmaxf(cdp - radius[(size_t)b * NC + idx], 0.0f);

    // c2p term: group of S=32 consecutive minsq entries = one 32-lane half
    float cd = sqrtf(fmaxf(__uint_as_float(minsq[i]), 1e-12f));
    #pragma unroll
    for (int o = 16; o > 0; o >>= 1) cd = fmaxf(cd, __shfl_xor(cd, o, 64));

    float contrib = val * (1.0f / N) +
                    (((tid & 31) == 0) ? cd * (1.0f / NC) : 0.0f);
    #pragma unroll
    for (int o = 32; o > 0; o >>= 1) contrib += __shfl_down(contrib, o);
    __shared__ float wsum[4];
    if ((tid & 63) == 0) wsum[tid >> 6] = contrib;
    __syncthreads();
    if (tid == 0) atomicAdd(&acc[0], wsum[0] + wsum[1] + wsum[2] + wsum[3]);

    __shared__ int lastf;
    if (tid == 0) {
        __threadfence();
        unsigned old = atomicAdd(counter, 1u);
        lastf = (old == (unsigned)(gridDim.x - 1));
    }
    __syncthreads();
    if (lastf && tid == 0)
        out[0] = atomicAdd(&acc[0], 0.0f) * (1.0f / B);
}

extern "C" void kernel_launch(void* const* d_in, const int* in_sizes, int n_in,
                              void* d_out, int out_size, void* d_ws, size_t ws_size,
                              hipStream_t stream) {
    const float* centers = (const float*)d_in[0];
    const float* radius  = (const float*)d_in[1];
    const float* xyz     = (const float*)d_in[2];
    const float* sp      = (const float*)d_in[3];
    float* out = (float*)d_out;

    unsigned short*     Afrag = (unsigned short*)d_ws;                        // 2 MB
    unsigned long long* best  = (unsigned long long*)((char*)d_ws + (size_t)B * N * 32);
    unsigned* minsq  = (unsigned*)((char*)best + (size_t)B * N * 8);          // 256 KB
    float*    acc    = (float*)((char*)minsq + (size_t)B * NSP * 4);
    unsigned* counter = (unsigned*)acc + 1;

    hipLaunchKernelGGL(k_prep, dim3(B * N / 256), dim3(256), 0, stream,
                       xyz, Afrag, best, minsq, (unsigned*)acc);
    hipLaunchKernelGGL(k_p2c, dim3(N / 256, NC / 256, B), dim3(256), 0, stream,
                       centers, xyz, best);
    hipLaunchKernelGGL(k_sp2p, dim3(GRIDX, NCH, B), dim3(BLKT), 0, stream,
                       sp, Afrag, minsq);
    hipLaunchKernelGGL(k_fin, dim3(B * N / 256), dim3(256), 0, stream,
                       best, minsq, xyz, radius, acc, counter, out);
}